// Round 9
// baseline (137.942 us; speedup 1.0000x reference)
//
#include <hip/hip_runtime.h>

// Problem constants
#define NROWS 512          // N
#define FEAT  8192         // NUM_CHANNELS*4*4
#define BDIM  64
#define CDIM  16
#define MCOLS 1024         // BDIM*CDIM
#define OUTC  8256         // FEAT + BDIM
#define KSPLIT 8
#define KCHUNK (FEAT / KSPLIT)     // 1024
#define MSIZE  (NROWS * MCOLS)     // 524288 floats = 2 MB

typedef __bf16 bf16x8 __attribute__((ext_vector_type(8)));
typedef float  floatx4 __attribute__((ext_vector_type(4)));
typedef _Float16 half2 __attribute__((ext_vector_type(2)));

#define AS1 __attribute__((address_space(1)))
#define AS3 __attribute__((address_space(3)))

// async global->LDS, 16B per lane. LDS dest = wave-uniform base + lane*16.
static __device__ __forceinline__ void gload16(const void* g, void* l) {
    __builtin_amdgcn_global_load_lds((AS1 void*)(g), (AS3 void*)(l), 16, 0, 0);
}

static __device__ __forceinline__ unsigned short f2bf(float f) {
    unsigned int x = __builtin_bit_cast(unsigned int, f);
    unsigned int r = (x + 0x7FFFu + ((x >> 16) & 1u)) >> 16;   // RNE
    return (unsigned short)r;
}

// pack two f32 -> f16x2 (round-toward-zero), as raw dword
static __device__ __forceinline__ unsigned int pk2h(float a, float b) {
    return __builtin_bit_cast(unsigned int, __builtin_amdgcn_cvt_pkrtz(a, b));
}

// packed |a-b| on two f16 lanes: v_pk_add(neg) + v_and (sign strip)
static __device__ __forceinline__ half2 absdiff2(unsigned int a, unsigned int b) {
    half2 d = __builtin_bit_cast(half2, a) - __builtin_bit_cast(half2, b);
    return __builtin_bit_cast(half2, __builtin_bit_cast(unsigned int, d) & 0x7FFF7FFFu);
}

// ---------------------------------------------------------------------------
// k_prep: 512 blocks x 512 thr (16 waves/CU of independent streams).
//  blocks [0,256):   x fp32 -> bf16 xb + copy x into out[:, :8192]
//  blocks [256,512): T (8192x1024 f32) -> Tt (1024x8192 bf16), 64x64 tiles,
//                    2 concurrent per block, 8 tiles per block.
// ---------------------------------------------------------------------------
__global__ __launch_bounds__(512, 2) void k_prep(const float* __restrict__ x,
                                                 const float* __restrict__ T,
                                                 unsigned short* __restrict__ xb,
                                                 unsigned short* __restrict__ Tt,
                                                 float* __restrict__ out) {
    __shared__ __align__(16) float lds[2][64][65];   // +1 pad: 2-way only (free)
    int bid = blockIdx.x, t = threadIdx.x;
    if (bid < 256) {
#pragma unroll
        for (int u = 0; u < 8; ++u) {
            int gid = bid * 4096 + u * 512 + t;      // float4 index, 1M total
            float4 v = *(const float4*)(x + (size_t)gid * 4);
            ushort4 uu;
            uu.x = f2bf(v.x); uu.y = f2bf(v.y); uu.z = f2bf(v.z); uu.w = f2bf(v.w);
            *(ushort4*)(xb + (size_t)gid * 4) = uu;
            int row = gid >> 11, col4 = gid & 2047;
            *(float4*)(out + (size_t)row * OUTC + col4 * 4) = v;
        }
    } else {
        int b2 = bid - 256;
        int sub = t >> 8, tt = t & 255;
        for (int u = 0; u < 4; ++u) {
            int tile = b2 * 8 + u * 2 + sub;         // 2048 tiles total
            int kt = tile & 127, nt = tile >> 7;     // 128 k-tiles x 16 n-tiles
            __syncthreads();                          // protect prior reads
            int kk = tt >> 2, q = tt & 3;
#pragma unroll
            for (int p = 0; p < 4; ++p) {
                int c4 = q + p * 4;
                float4 v = *(const float4*)(T + (size_t)(kt * 64 + kk) * MCOLS + nt * 64 + c4 * 4);
                lds[sub][kk][c4 * 4 + 0] = v.x; lds[sub][kk][c4 * 4 + 1] = v.y;
                lds[sub][kk][c4 * 4 + 2] = v.z; lds[sub][kk][c4 * 4 + 3] = v.w;
            }
            __syncthreads();
            int nr = tt >> 2, ck = tt & 3;
            unsigned int wv[8];
#pragma unroll
            for (int j = 0; j < 8; ++j) {
                unsigned int lo = f2bf(lds[sub][ck * 16 + j * 2 + 0][nr]);
                unsigned int hi = f2bf(lds[sub][ck * 16 + j * 2 + 1][nr]);
                wv[j] = lo | (hi << 16);
            }
            uint4* dst = (uint4*)(Tt + (size_t)(nt * 64 + nr) * FEAT + kt * 64 + ck * 16);
            dst[0] = make_uint4(wv[0], wv[1], wv[2], wv[3]);
            dst[1] = make_uint4(wv[4], wv[5], wv[6], wv[7]);
        }
    }
}

// ---------------------------------------------------------------------------
// k_gemm: (verbatim from R7 — passed) M = x@T, bf16 MFMA 16x16x32.
// 128x64 tile, 256 thr (4 waves, 2x2), BK=64, global_load_lds, split-K=8.
// grid = 4(mt) x 16(nt) x 8(ks) = 512 blocks -> exactly 2 blocks/CU.
// ---------------------------------------------------------------------------
__global__ __launch_bounds__(256, 2) void k_gemm(const unsigned short* __restrict__ xb,
                                                 const unsigned short* __restrict__ Tt,
                                                 float* __restrict__ Mp) {
    __shared__ __align__(16) unsigned short ldsA[128 * 64];   // 16 KB, 16 panels
    __shared__ __align__(16) unsigned short ldsB[64 * 64];    // 8 KB, 8 panels
    int bid = blockIdx.x, t = threadIdx.x;
    int mt = bid & 3, nt = (bid >> 2) & 15, ks = bid >> 6;
    int m0 = mt * 128, n0 = nt * 64, kbase = ks * KCHUNK;
    int w = t >> 6, l = t & 63;

    int c  = (l & 3) ^ ((l >> 3) & 3);
    int lr = l >> 2;
    const unsigned short* gA0 = xb + (size_t)(m0 + w * 32 + lr) * FEAT + kbase + c * 8;
    const unsigned short* gA1 = gA0 + (size_t)16 * FEAT;
    const unsigned short* gB0 = Tt + (size_t)(n0 + w * 16 + lr) * FEAT + kbase + c * 8;
    unsigned short* lA00 = ldsA + (4 * w + 0) * 512;
    unsigned short* lA01 = ldsA + (4 * w + 1) * 512;
    unsigned short* lA10 = ldsA + (4 * w + 2) * 512;
    unsigned short* lA11 = ldsA + (4 * w + 3) * 512;
    unsigned short* lB0  = ldsB + (2 * w + 0) * 512;
    unsigned short* lB1  = ldsB + (2 * w + 1) * 512;

    int wr = w >> 1, wc = w & 1, fm = l & 15, fq = l >> 4;
    int fo = fm * 32 + ((fq ^ ((fm >> 1) & 3)) * 8);
    const unsigned short* paB = ldsA + (wr * 8) * 512 + fo;
    const unsigned short* pbB = ldsB + (wc * 4) * 512 + fo;

    floatx4 acc[4][2] = {};

    for (int kk = 0; kk < KCHUNK; kk += 64) {
        __syncthreads();
        gload16(gA0 + kk,      lA00);
        gload16(gA0 + kk + 32, lA01);
        gload16(gA1 + kk,      lA10);
        gload16(gA1 + kk + 32, lA11);
        gload16(gB0 + kk,      lB0);
        gload16(gB0 + kk + 32, lB1);
        __syncthreads();
#pragma unroll
        for (int h = 0; h < 2; ++h) {
            bf16x8 af[4], bfr[2];
#pragma unroll
            for (int a = 0; a < 4; ++a) af[a]  = *(const bf16x8*)(paB + (a * 2 + h) * 512);
#pragma unroll
            for (int b = 0; b < 2; ++b) bfr[b] = *(const bf16x8*)(pbB + (b * 2 + h) * 512);
#pragma unroll
            for (int a = 0; a < 4; ++a)
#pragma unroll
                for (int b = 0; b < 2; ++b)
                    acc[a][b] = __builtin_amdgcn_mfma_f32_16x16x32_bf16(af[a], bfr[b], acc[a][b], 0, 0, 0);
        }
    }

    float* outp = Mp + (size_t)ks * MSIZE;
    int gr0 = m0 + wr * 64, gc0 = n0 + wc * 32;
#pragma unroll
    for (int a = 0; a < 4; ++a)
#pragma unroll
        for (int r = 0; r < 4; ++r) {
            int row = gr0 + a * 16 + fq * 4 + r;
#pragma unroll
            for (int b = 0; b < 2; ++b)
                outp[(size_t)row * MCOLS + gc0 + b * 16 + fm] = acc[a][b][r];
        }
}

// ---------------------------------------------------------------------------
// k_pair: o[i,b] = sum_j exp(-L1(M_i,M_j)) -> out[:, 8192:8256].
// Split-K reduce fused into staging; M stored in LDS as packed f16x2
// (8 dwords/row, stride 12 dwords -> 16B-aligned rows). Distances via
// v_pk_add_f16 + packed-abs (sign-strip). j wave-uniform -> broadcast b128.
// 256 blocks: b = bid&63, itp = bid>>6; groups g = t>>8 -> it = itp*2+g;
// 4 waves per group split j (128 each).
// ---------------------------------------------------------------------------
__global__ __launch_bounds__(512, 2) void k_pair(const float* __restrict__ Mp,
                                                 float* __restrict__ out) {
    __shared__ __align__(16) unsigned int ldsMh[NROWS * 12];  // 24576 B
    __shared__ float partial[8][64];
    int bid = blockIdx.x, t = threadIdx.x;
    int b = bid & 63, itp = bid >> 6;
#pragma unroll
    for (int p = 0; p < 4; ++p) {
        int idx = t + p * 512;                // 2048 float4-slots (512 j x 4)
        int j = idx >> 2, c4 = idx & 3;
        const float* base = Mp + (size_t)j * MCOLS + b * CDIM + c4 * 4;
        float4 s = *(const float4*)base;
#pragma unroll
        for (int k = 1; k < KSPLIT; ++k) {
            float4 v = *(const float4*)(base + (size_t)k * MSIZE);
            s.x += v.x; s.y += v.y; s.z += v.z; s.w += v.w;
        }
        uint2 wv;
        wv.x = pk2h(s.x, s.y);
        wv.y = pk2h(s.z, s.w);
        *(uint2*)&ldsMh[j * 12 + c4 * 2] = wv;
    }
    __syncthreads();

    int lane = t & 63, w = t >> 6, g = t >> 8, wg = (t >> 6) & 3;
    int i = (itp * 2 + g) * 64 + lane;
    uint4 miA = *(const uint4*)&ldsMh[i * 12];       // c0..7
    uint4 miB = *(const uint4*)&ldsMh[i * 12 + 4];   // c8..15

    float acc = 0.0f;
    for (int jj = wg * 128; jj < wg * 128 + 128; ++jj) {
        uint4 mjA = *(const uint4*)&ldsMh[jj * 12];
        uint4 mjB = *(const uint4*)&ldsMh[jj * 12 + 4];
        half2 sA = (absdiff2(miA.x, mjA.x) + absdiff2(miA.y, mjA.y)) +
                   (absdiff2(miA.z, mjA.z) + absdiff2(miA.w, mjA.w));
        half2 sB = (absdiff2(miB.x, mjB.x) + absdiff2(miB.y, mjB.y)) +
                   (absdiff2(miB.z, mjB.z) + absdiff2(miB.w, mjB.w));
        half2 s = sA + sB;
        float d = (float)s.x + (float)s.y;
        acc += __expf(-d);
    }
    partial[w][lane] = acc;
    __syncthreads();
    if ((t & 255) < 64) {
        int ii = (itp * 2 + g) * 64 + (t & 63);
        float o = partial[g * 4 + 0][t & 63] + partial[g * 4 + 1][t & 63] +
                  partial[g * 4 + 2][t & 63] + partial[g * 4 + 3][t & 63];
        out[(size_t)ii * OUTC + FEAT + b] = o;
    }
}

// ---------------------------------------------------------------------------
extern "C" void kernel_launch(void* const* d_in, const int* in_sizes, int n_in,
                              void* d_out, int out_size, void* d_ws, size_t ws_size,
                              hipStream_t stream) {
    const float* x = (const float*)d_in[0];      // (512, 8192)
    const float* T = (const float*)d_in[1];      // (8192, 1024)
    float* out = (float*)d_out;                  // (512, 8256)

    // ws layout: xb 8MB | Tt 16MB | Mp 8x2MB=16MB  (40MB total)
    unsigned short* xb = (unsigned short*)d_ws;
    unsigned short* Tt = (unsigned short*)((char*)d_ws + (8u << 20));
    float*          Mp = (float*)((char*)d_ws + (24u << 20));

    k_prep<<<512, 512, 0, stream>>>(x, T, xb, Tt, out);
    k_gemm<<<512, 256, 0, stream>>>(xb, Tt, Mp);
    k_pair<<<256, 512, 0, stream>>>(Mp, out);
}